// Round 8
// baseline (139.509 us; speedup 1.0000x reference)
//
#include <hip/hip_runtime.h>

// LiftSplatShoot: out(B,N,3+C,H,W,D) = concat(world, feats_broadcast)
// B=4 N=6 C=80 H=16 W=44 D=59 -> 82,739,712 fp32 (~331 MB). Write-bound.
// Round 8: same flat sweep as round 7, but LOW OCCUPANCY (256 blocks =
// 4 waves/CU = 12.5%, matching the 7 TB/s fill kernel's 10.8%) + unroll 4
// for per-wave MLP. Theory: 32 waves/CU of write streams thrash the
// store queue / L2 write path; few fat streams >> many thin ones.

#define BB 4
#define NN 6
#define CC 80
#define HH 16
#define WW 44
#define DD 59
#define BN (BB*NN)        // 24
#define PP (HH*WW)        // 704
#define CHO (CC+3)        // 83
#define WD (WW*DD)        // 2596
#define DSTEP (0.9f/58.f)
#define NF4 20684928u     // 82,739,712 / 4
#define SWEEPB 256

typedef float fx4 __attribute__((ext_vector_type(4)));
typedef unsigned int uint;

__device__ inline float waveMax(float v) {
#pragma unroll
    for (int o = 32; o; o >>= 1) v = fmaxf(v, __shfl_xor(v, o));
    return v;
}
__device__ inline float waveSum(float v) {
#pragma unroll
    for (int o = 32; o; o >>= 1) v += __shfl_xor(v, o);
    return v;
}

// One block per bn: softmax of channel 79, rows 0..2 of M = R*K^-1,
// Vw[(bn*3+ch)*704 + p] = ray*dlast, Tarr[bn*3+ch] = t.
__global__ __launch_bounds__(256) void lss_prep(const float* __restrict__ feats,
                                                const float* __restrict__ intr,
                                                const float* __restrict__ extr,
                                                float* __restrict__ Vw,
                                                float* __restrict__ Tarr) {
    const int bn = blockIdx.x;
    const int tid = threadIdx.x;
    __shared__ float sf[PP];
    __shared__ float sred[4];
    __shared__ float sbc[2];

    const float* f = feats + ((size_t)bn * CC + (CC - 1)) * PP;
    float m = -1e30f;
    for (int p = tid; p < PP; p += 256) { float v = f[p]; sf[p] = v; m = fmaxf(m, v); }
    m = waveMax(m);
    if ((tid & 63) == 0) sred[tid >> 6] = m;
    __syncthreads();
    if (tid == 0) sbc[0] = fmaxf(fmaxf(sred[0], sred[1]), fmaxf(sred[2], sred[3]));
    __syncthreads();
    const float mm = sbc[0];
    float s = 0.f;
    for (int p = tid; p < PP; p += 256) { float e = expf(sf[p] - mm); sf[p] = e; s += e; }
    s = waveSum(s);
    if ((tid & 63) == 0) sred[tid >> 6] = s;
    __syncthreads();
    if (tid == 0) sbc[1] = sred[0] + sred[1] + sred[2] + sred[3];
    __syncthreads();
    const float inv = 1.0f / sbc[1];

    // K^-1 (uniform across threads)
    const float* K = intr + bn * 16;
    float a = K[0], b = K[1], c = K[2];
    float d = K[4], e = K[5], ff = K[6];
    float g = K[8], h9 = K[9], i9 = K[10];
    float det = a * (e * i9 - ff * h9) - b * (d * i9 - ff * g) + c * (d * h9 - e * g);
    float id = 1.0f / det;
    float kinv[9] = {
        (e * i9 - ff * h9) * id, (c * h9 - b * i9) * id, (b * ff - c * e) * id,
        (ff * g - d * i9) * id,  (a * i9 - c * g) * id,  (c * d - a * ff) * id,
        (d * h9 - e * g) * id,   (b * g - a * h9) * id,  (a * e - b * d) * id
    };
    const float* E = extr + bn * 16;
#pragma unroll
    for (int ch = 0; ch < 3; ++ch) {
        float M0 = E[ch * 4 + 0] * kinv[0] + E[ch * 4 + 1] * kinv[3] + E[ch * 4 + 2] * kinv[6];
        float M1 = E[ch * 4 + 0] * kinv[1] + E[ch * 4 + 1] * kinv[4] + E[ch * 4 + 2] * kinv[7];
        float M2 = E[ch * 4 + 0] * kinv[2] + E[ch * 4 + 1] * kinv[5] + E[ch * 4 + 2] * kinv[8];
        float* vrow = Vw + (size_t)(bn * 3 + ch) * PP;
        for (int p = tid; p < PP; p += 256) {
            int hl = p / WW;
            int w  = p - hl * WW;
            float ray = M0 * (float)w + M1 * (float)hl + M2;
            vrow[p] = ray * sf[p] * inv;
        }
        if (tid == 0) Tarr[bn * 3 + ch] = E[ch * 4 + 3];
    }
}

// Flat grid-stride expansion: one float4 of output per thread-iteration.
__global__ __launch_bounds__(256) void lss_sweep(const float* __restrict__ feats,
                                                 const float* __restrict__ Vw,
                                                 const float* __restrict__ Tarr,
                                                 float* __restrict__ out) {
    const uint stride = gridDim.x * 256u;
#pragma unroll 4
    for (uint fq = blockIdx.x * 256u + threadIdx.x; fq < NF4; fq += stride) {
        uint r  = fq / 649u;           // global row (s*16 + hl)
        uint q  = fq - 649u * r;       // float4 index within row
        uint c  = q << 2;              // element col in row
        uint w  = c / 59u;
        uint d  = c - 59u * w;
        uint s  = r >> 4;              // slab = bn*83 + ch
        uint hl = r & 15u;
        uint bn = s / 83u;
        uint ch = s - 83u * bn;
        uint cw = (d >= 56u) ? 1u : 0u;   // does this float4 cross w -> w+1?
        uint kc = 59u - d;                 // first k that uses vB (>=4 if no cross)

        fx4 v;
        if (ch < 3u) {
            uint wrow = s - 80u * bn;      // bn*3 + ch
            uint widx = wrow * (uint)PP + hl * 44u + w;
            float T  = Tarr[wrow];
            float vA = Vw[widx];
            float vB = Vw[widx + cw];
#pragma unroll
            for (int k = 0; k < 4; ++k) {
                bool crossed = ((uint)k >= kc);
                float val = crossed ? vB : vA;
                uint dk = d + (uint)k - (crossed ? 59u : 0u);
                v[k] = val * (0.1f + (float)dk * DSTEP) + T;
            }
        } else {
            uint fi = (s - 3u * bn - 3u) * (uint)PP + hl * 44u + w;
            float vA = feats[fi];
            float vB = feats[fi + cw];
#pragma unroll
            for (int k = 0; k < 4; ++k) v[k] = ((uint)k >= kc) ? vB : vA;
        }
        ((fx4*)out)[fq] = v;
    }
}

extern "C" void kernel_launch(void* const* d_in, const int* in_sizes, int n_in,
                              void* d_out, int out_size, void* d_ws, size_t ws_size,
                              hipStream_t stream) {
    const float* feats = (const float*)d_in[0];
    const float* intr  = (const float*)d_in[1];
    const float* extr  = (const float*)d_in[2];
    float* out  = (float*)d_out;
    float* Vw   = (float*)d_ws;                 // 72*704 = 50688 floats
    float* Tarr = (float*)d_ws + 50688 + 16;    // 72 floats

    lss_prep<<<BN, 256, 0, stream>>>(feats, intr, extr, Vw, Tarr);
    lss_sweep<<<SWEEPB, 256, 0, stream>>>(feats, Vw, Tarr, out);
}

// Round 9
// 72.871 us; speedup vs baseline: 1.9145x; 1.9145x over previous
//
#include <hip/hip_runtime.h>

// LiftSplatShoot: out(B,N,3+C,H,W,D) = concat(world, feats_broadcast)
// B=4 N=6 C=80 H=16 W=44 D=59 -> 82,739,712 fp32 (~331 MB). Write-bound.
// Round 9: flat sweep (r7 winner) at 32B/thread: slab = 704*59 = 41536
// divisible by 8, and an 8-element depth run crosses at most one spatial
// boundary (always p -> p+1 in flat (h,w) order). Halves load count and
// ~3x less magic-div work per byte vs r7. Full occupancy (r8 lesson).

#define BB 4
#define NN 6
#define CC 80
#define HH 16
#define WW 44
#define DD 59
#define BN (BB*NN)        // 24
#define PP (HH*WW)        // 704
#define CHO (CC+3)        // 83
#define WD (WW*DD)        // 2596
#define DSTEP (0.9f/58.f)
#define NF8 10342464u     // 82,739,712 / 8
#define SWEEPB 2048

typedef float fx4 __attribute__((ext_vector_type(4)));
typedef unsigned int uint;

__device__ inline float waveMax(float v) {
#pragma unroll
    for (int o = 32; o; o >>= 1) v = fmaxf(v, __shfl_xor(v, o));
    return v;
}
__device__ inline float waveSum(float v) {
#pragma unroll
    for (int o = 32; o; o >>= 1) v += __shfl_xor(v, o);
    return v;
}

// One block per bn: softmax of channel 79, rows 0..2 of M = R*K^-1,
// Vw[(bn*3+ch)*704 + p] = ray*dlast, Tarr[bn*3+ch] = t.
__global__ __launch_bounds__(256) void lss_prep(const float* __restrict__ feats,
                                                const float* __restrict__ intr,
                                                const float* __restrict__ extr,
                                                float* __restrict__ Vw,
                                                float* __restrict__ Tarr) {
    const int bn = blockIdx.x;
    const int tid = threadIdx.x;
    __shared__ float sf[PP];
    __shared__ float sred[4];
    __shared__ float sbc[2];

    const float* f = feats + ((size_t)bn * CC + (CC - 1)) * PP;
    float m = -1e30f;
    for (int p = tid; p < PP; p += 256) { float v = f[p]; sf[p] = v; m = fmaxf(m, v); }
    m = waveMax(m);
    if ((tid & 63) == 0) sred[tid >> 6] = m;
    __syncthreads();
    if (tid == 0) sbc[0] = fmaxf(fmaxf(sred[0], sred[1]), fmaxf(sred[2], sred[3]));
    __syncthreads();
    const float mm = sbc[0];
    float s = 0.f;
    for (int p = tid; p < PP; p += 256) { float e = expf(sf[p] - mm); sf[p] = e; s += e; }
    s = waveSum(s);
    if ((tid & 63) == 0) sred[tid >> 6] = s;
    __syncthreads();
    if (tid == 0) sbc[1] = sred[0] + sred[1] + sred[2] + sred[3];
    __syncthreads();
    const float inv = 1.0f / sbc[1];

    // K^-1 (uniform across threads)
    const float* K = intr + bn * 16;
    float a = K[0], b = K[1], c = K[2];
    float d = K[4], e = K[5], ff = K[6];
    float g = K[8], h9 = K[9], i9 = K[10];
    float det = a * (e * i9 - ff * h9) - b * (d * i9 - ff * g) + c * (d * h9 - e * g);
    float id = 1.0f / det;
    float kinv[9] = {
        (e * i9 - ff * h9) * id, (c * h9 - b * i9) * id, (b * ff - c * e) * id,
        (ff * g - d * i9) * id,  (a * i9 - c * g) * id,  (c * d - a * ff) * id,
        (d * h9 - e * g) * id,   (b * g - a * h9) * id,  (a * e - b * d) * id
    };
    const float* E = extr + bn * 16;
#pragma unroll
    for (int ch = 0; ch < 3; ++ch) {
        float M0 = E[ch * 4 + 0] * kinv[0] + E[ch * 4 + 1] * kinv[3] + E[ch * 4 + 2] * kinv[6];
        float M1 = E[ch * 4 + 0] * kinv[1] + E[ch * 4 + 1] * kinv[4] + E[ch * 4 + 2] * kinv[7];
        float M2 = E[ch * 4 + 0] * kinv[2] + E[ch * 4 + 1] * kinv[5] + E[ch * 4 + 2] * kinv[8];
        float* vrow = Vw + (size_t)(bn * 3 + ch) * PP;
        for (int p = tid; p < PP; p += 256) {
            int hl = p / WW;
            int w  = p - hl * WW;
            float ray = M0 * (float)w + M1 * (float)hl + M2;
            vrow[p] = ray * sf[p] * inv;
        }
        if (tid == 0) Tarr[bn * 3 + ch] = E[ch * 4 + 3];
    }
}

// Flat grid-stride expansion: 8 consecutive output floats per thread-iter.
__global__ __launch_bounds__(256) void lss_sweep(const float* __restrict__ feats,
                                                 const float* __restrict__ Vw,
                                                 const float* __restrict__ Tarr,
                                                 float* __restrict__ out) {
    const uint stride = gridDim.x * 256u;
    for (uint g = blockIdx.x * 256u + threadIdx.x; g < NF8; g += stride) {
        uint sl = g / 5192u;            // slab = bn*83 + ch   (5192 = 41536/8)
        uint e8 = (g - sl * 5192u) << 3;// element within slab [0, 41536)
        uint p  = e8 / 59u;             // flat spatial (h*44+w), <= 703
        uint d0 = e8 - 59u * p;         // depth of first element
        uint bn = sl / 83u;
        uint ch = sl - 83u * bn;
        uint kc = 59u - d0;             // first k using src[p+1] (>=8 if none)
        uint cw = (kc < 8u) ? 1u : 0u;

        float vv[8];
        if (ch < 3u) {
            uint wrow = bn * 3u + ch;
            const float* src = Vw + wrow * (uint)PP;
            float T  = Tarr[wrow];
            float vA = src[p];
            float vB = src[p + cw];
#pragma unroll
            for (int k = 0; k < 8; ++k) {
                bool cr = ((uint)k >= kc);
                float val = cr ? vB : vA;
                uint dk = d0 + (uint)k - (cr ? 59u : 0u);
                vv[k] = val * (0.1f + (float)dk * DSTEP) + T;
            }
        } else {
            const float* src = feats + (bn * (uint)CC + (ch - 3u)) * (uint)PP;
            float vA = src[p];
            float vB = src[p + cw];
#pragma unroll
            for (int k = 0; k < 8; ++k) vv[k] = ((uint)k >= kc) ? vB : vA;
        }
        fx4 lo, hi;
        lo.x = vv[0]; lo.y = vv[1]; lo.z = vv[2]; lo.w = vv[3];
        hi.x = vv[4]; hi.y = vv[5]; hi.z = vv[6]; hi.w = vv[7];
        ((fx4*)out)[2u * g]      = lo;
        ((fx4*)out)[2u * g + 1u] = hi;
    }
}

extern "C" void kernel_launch(void* const* d_in, const int* in_sizes, int n_in,
                              void* d_out, int out_size, void* d_ws, size_t ws_size,
                              hipStream_t stream) {
    const float* feats = (const float*)d_in[0];
    const float* intr  = (const float*)d_in[1];
    const float* extr  = (const float*)d_in[2];
    float* out  = (float*)d_out;
    float* Vw   = (float*)d_ws;                 // 72*704 = 50688 floats
    float* Tarr = (float*)d_ws + 50688 + 16;    // 72 floats

    lss_prep<<<BN, 256, 0, stream>>>(feats, intr, extr, Vw, Tarr);
    lss_sweep<<<SWEEPB, 256, 0, stream>>>(feats, Vw, Tarr, out);
}

// Round 10
// 66.060 us; speedup vs baseline: 2.1119x; 1.1031x over previous
//
#include <hip/hip_runtime.h>

// LiftSplatShoot: out(B,N,3+C,H,W,D) = concat(world, feats_broadcast)
// B=4 N=6 C=80 H=16 W=44 D=59 -> 82,739,712 fp32 (~331 MB). Write-bound.
// Round 10: single fused kernel, r7's dense flat sweep retained.
//  - blocks 0..71: one world slab each (own softmax+M in LDS, write 166KB)
//  - blocks 72..2119: branch-free grid-stride over the 1920 feature slabs
// No prep launch, no workspace, same 1KB-aligned dense wave bursts.

#define BB 4
#define NN 6
#define CC 80
#define HH 16
#define WW 44
#define DD 59
#define BN (BB*NN)        // 24
#define PP (HH*WW)        // 704
#define CHO (CC+3)        // 83
#define DSTEP (0.9f/58.f)
#define Q4S 10384u        // float4s per slab (41536/4)
#define NFS 1920u         // feature slabs (24*80)
#define NFF4 (NFS*Q4S)    // feature float4s = 19,937,280
#define WBLK 72           // world blocks
#define FBLK 2048         // feature blocks

typedef float fx4 __attribute__((ext_vector_type(4)));
typedef unsigned int uint;

__device__ inline float waveMax(float v) {
#pragma unroll
    for (int o = 32; o; o >>= 1) v = fmaxf(v, __shfl_xor(v, o));
    return v;
}
__device__ inline float waveSum(float v) {
#pragma unroll
    for (int o = 32; o; o >>= 1) v += __shfl_xor(v, o);
    return v;
}

__global__ __launch_bounds__(256) void lss_fused(const float* __restrict__ feats,
                                                 const float* __restrict__ intr,
                                                 const float* __restrict__ extr,
                                                 float* __restrict__ out) {
    const int blk = blockIdx.x;
    const int tid = threadIdx.x;

    __shared__ float sf[PP];
    __shared__ float vw[PP + 1];
    __shared__ float sred[4];
    __shared__ float sbc[2];

    if (blk < WBLK) {
        // ---------------- world slab: bn = blk/3, ch = blk%3 ----------------
        const int bn = blk / 3;
        const int ch = blk - 3 * bn;

        // softmax of channel 79 into sf
        const float* f = feats + ((size_t)bn * CC + (CC - 1)) * PP;
        float m = -1e30f;
        for (int p = tid; p < PP; p += 256) { float v = f[p]; sf[p] = v; m = fmaxf(m, v); }
        m = waveMax(m);
        if ((tid & 63) == 0) sred[tid >> 6] = m;
        __syncthreads();
        if (tid == 0) sbc[0] = fmaxf(fmaxf(sred[0], sred[1]), fmaxf(sred[2], sred[3]));
        __syncthreads();
        const float mm = sbc[0];
        float s = 0.f;
        for (int p = tid; p < PP; p += 256) { float e = expf(sf[p] - mm); sf[p] = e; s += e; }
        s = waveSum(s);
        if ((tid & 63) == 0) sred[tid >> 6] = s;
        __syncthreads();
        if (tid == 0) sbc[1] = sred[0] + sred[1] + sred[2] + sred[3];
        __syncthreads();
        const float inv = 1.0f / sbc[1];

        // row ch of M = R*K^-1 (uniform)
        const float* K = intr + bn * 16;
        float a = K[0], b = K[1], c = K[2];
        float d = K[4], e = K[5], ff = K[6];
        float g = K[8], h9 = K[9], i9 = K[10];
        float det = a * (e * i9 - ff * h9) - b * (d * i9 - ff * g) + c * (d * h9 - e * g);
        float id = 1.0f / det;
        float kinv[9] = {
            (e * i9 - ff * h9) * id, (c * h9 - b * i9) * id, (b * ff - c * e) * id,
            (ff * g - d * i9) * id,  (a * i9 - c * g) * id,  (c * d - a * ff) * id,
            (d * h9 - e * g) * id,   (b * g - a * h9) * id,  (a * e - b * d) * id
        };
        const float* E = extr + bn * 16;
        float M0 = E[ch * 4 + 0] * kinv[0] + E[ch * 4 + 1] * kinv[3] + E[ch * 4 + 2] * kinv[6];
        float M1 = E[ch * 4 + 0] * kinv[1] + E[ch * 4 + 1] * kinv[4] + E[ch * 4 + 2] * kinv[7];
        float M2 = E[ch * 4 + 0] * kinv[2] + E[ch * 4 + 1] * kinv[5] + E[ch * 4 + 2] * kinv[8];
        const float T = E[ch * 4 + 3];

        for (int p = tid; p < PP; p += 256) {
            int hl = p / WW;
            int w  = p - hl * WW;
            float ray = M0 * (float)w + M1 * (float)hl + M2;
            vw[p] = ray * sf[p] * inv;
        }
        if (tid == 0) vw[PP] = 0.f;
        __syncthreads();

        // write the slab: out float4s [s*Q4S, (s+1)*Q4S)
        const uint s0 = (uint)(bn * CHO + ch) * Q4S;
        for (uint q = tid; q < Q4S; q += 256u) {
            uint c4 = q << 2;
            uint p  = c4 / 59u;
            uint d0 = c4 - 59u * p;
            uint kc = 59u - d0;              // first k using p+1 (>=4 if none)
            uint cw = (kc < 4u) ? 1u : 0u;
            float vA = vw[p];
            float vB = vw[p + cw];
            fx4 r;
#pragma unroll
            for (int k = 0; k < 4; ++k) {
                bool cr = ((uint)k >= kc);
                float val = cr ? vB : vA;
                uint dk = d0 + (uint)k - (cr ? 59u : 0u);
                r[k] = val * (0.1f + (float)dk * DSTEP) + T;
            }
            ((fx4*)out)[s0 + q] = r;
        }
    } else {
        // ---------------- feature slabs: branch-free flat sweep ----------------
        const uint stride = FBLK * 256u;
        for (uint g = (uint)(blk - WBLK) * 256u + tid; g < NFF4; g += stride) {
            uint fs = g / Q4S;              // feature slab [0,1920)
            uint r4 = g - fs * Q4S;         // float4 within slab
            uint c4 = r4 << 2;
            uint p  = c4 / 59u;
            uint d0 = c4 - 59u * p;
            uint bn = fs / 80u;
            uint chf = fs - 80u * bn;       // 0..79
            uint kc = 59u - d0;
            uint cw = (kc < 4u) ? 1u : 0u;

            const float* src = feats + ((size_t)bn * CC + chf) * PP;
            float vA = src[p];
            float vB = src[p + cw];
            fx4 r;
#pragma unroll
            for (int k = 0; k < 4; ++k) r[k] = ((uint)k >= kc) ? vB : vA;

            uint s = bn * (uint)CHO + 3u + chf;   // output slab index
            ((fx4*)out)[s * Q4S + r4] = r;
        }
    }
}

extern "C" void kernel_launch(void* const* d_in, const int* in_sizes, int n_in,
                              void* d_out, int out_size, void* d_ws, size_t ws_size,
                              hipStream_t stream) {
    const float* feats = (const float*)d_in[0];
    const float* intr  = (const float*)d_in[1];
    const float* extr  = (const float*)d_in[2];
    float* out = (float*)d_out;

    lss_fused<<<WBLK + FBLK, 256, 0, stream>>>(feats, intr, extr, out);
}

// Round 11
// 63.046 us; speedup vs baseline: 2.2128x; 1.0478x over previous
//
#include <hip/hip_runtime.h>

// LiftSplatShoot: out(B,N,3+C,H,W,D) = concat(world, feats_broadcast)
// B=4 N=6 C=80 H=16 W=44 D=59 -> 82,739,712 fp32 (~331 MB). Write-bound.
// Round 11: r10 with EXACT grid fit: 72 world + 1976 feature = 2048 blocks
// = exactly 8 blocks/CU (LDS 5.7KB*8, 2048 threads/CU both at cap). r10's
// 2120 blocks forced 72 CUs to serialize a 9th block -> low-residency tail
// (r8: this stream collapses at low residency). One variable changed.

#define BB 4
#define NN 6
#define CC 80
#define HH 16
#define WW 44
#define DD 59
#define BN (BB*NN)        // 24
#define PP (HH*WW)        // 704
#define CHO (CC+3)        // 83
#define DSTEP (0.9f/58.f)
#define Q4S 10384u        // float4s per slab (41536/4)
#define NFS 1920u         // feature slabs (24*80)
#define NFF4 (NFS*Q4S)    // feature float4s = 19,937,280
#define WBLK 72           // world blocks
#define FBLK 1976         // feature blocks (72+1976 = 2048 = 8/CU exact)

typedef float fx4 __attribute__((ext_vector_type(4)));
typedef unsigned int uint;

__device__ inline float waveMax(float v) {
#pragma unroll
    for (int o = 32; o; o >>= 1) v = fmaxf(v, __shfl_xor(v, o));
    return v;
}
__device__ inline float waveSum(float v) {
#pragma unroll
    for (int o = 32; o; o >>= 1) v += __shfl_xor(v, o);
    return v;
}

__global__ __launch_bounds__(256) void lss_fused(const float* __restrict__ feats,
                                                 const float* __restrict__ intr,
                                                 const float* __restrict__ extr,
                                                 float* __restrict__ out) {
    const int blk = blockIdx.x;
    const int tid = threadIdx.x;

    __shared__ float sf[PP];
    __shared__ float vw[PP + 1];
    __shared__ float sred[4];
    __shared__ float sbc[2];

    if (blk < WBLK) {
        // ---------------- world slab: bn = blk/3, ch = blk%3 ----------------
        const int bn = blk / 3;
        const int ch = blk - 3 * bn;

        // softmax of channel 79 into sf
        const float* f = feats + ((size_t)bn * CC + (CC - 1)) * PP;
        float m = -1e30f;
        for (int p = tid; p < PP; p += 256) { float v = f[p]; sf[p] = v; m = fmaxf(m, v); }
        m = waveMax(m);
        if ((tid & 63) == 0) sred[tid >> 6] = m;
        __syncthreads();
        if (tid == 0) sbc[0] = fmaxf(fmaxf(sred[0], sred[1]), fmaxf(sred[2], sred[3]));
        __syncthreads();
        const float mm = sbc[0];
        float s = 0.f;
        for (int p = tid; p < PP; p += 256) { float e = expf(sf[p] - mm); sf[p] = e; s += e; }
        s = waveSum(s);
        if ((tid & 63) == 0) sred[tid >> 6] = s;
        __syncthreads();
        if (tid == 0) sbc[1] = sred[0] + sred[1] + sred[2] + sred[3];
        __syncthreads();
        const float inv = 1.0f / sbc[1];

        // row ch of M = R*K^-1 (uniform)
        const float* K = intr + bn * 16;
        float a = K[0], b = K[1], c = K[2];
        float d = K[4], e = K[5], ff = K[6];
        float g = K[8], h9 = K[9], i9 = K[10];
        float det = a * (e * i9 - ff * h9) - b * (d * i9 - ff * g) + c * (d * h9 - e * g);
        float id = 1.0f / det;
        float kinv[9] = {
            (e * i9 - ff * h9) * id, (c * h9 - b * i9) * id, (b * ff - c * e) * id,
            (ff * g - d * i9) * id,  (a * i9 - c * g) * id,  (c * d - a * ff) * id,
            (d * h9 - e * g) * id,   (b * g - a * h9) * id,  (a * e - b * d) * id
        };
        const float* E = extr + bn * 16;
        float M0 = E[ch * 4 + 0] * kinv[0] + E[ch * 4 + 1] * kinv[3] + E[ch * 4 + 2] * kinv[6];
        float M1 = E[ch * 4 + 0] * kinv[1] + E[ch * 4 + 1] * kinv[4] + E[ch * 4 + 2] * kinv[7];
        float M2 = E[ch * 4 + 0] * kinv[2] + E[ch * 4 + 1] * kinv[5] + E[ch * 4 + 2] * kinv[8];
        const float T = E[ch * 4 + 3];

        for (int p = tid; p < PP; p += 256) {
            int hl = p / WW;
            int w  = p - hl * WW;
            float ray = M0 * (float)w + M1 * (float)hl + M2;
            vw[p] = ray * sf[p] * inv;
        }
        if (tid == 0) vw[PP] = 0.f;
        __syncthreads();

        // write the slab: out float4s [s*Q4S, (s+1)*Q4S)
        const uint s0 = (uint)(bn * CHO + ch) * Q4S;
        for (uint q = tid; q < Q4S; q += 256u) {
            uint c4 = q << 2;
            uint p  = c4 / 59u;
            uint d0 = c4 - 59u * p;
            uint kc = 59u - d0;              // first k using p+1 (>=4 if none)
            uint cw = (kc < 4u) ? 1u : 0u;
            float vA = vw[p];
            float vB = vw[p + cw];
            fx4 r;
#pragma unroll
            for (int k = 0; k < 4; ++k) {
                bool cr = ((uint)k >= kc);
                float val = cr ? vB : vA;
                uint dk = d0 + (uint)k - (cr ? 59u : 0u);
                r[k] = val * (0.1f + (float)dk * DSTEP) + T;
            }
            ((fx4*)out)[s0 + q] = r;
        }
    } else {
        // ---------------- feature slabs: branch-free flat sweep ----------------
        const uint stride = FBLK * 256u;
        for (uint g = (uint)(blk - WBLK) * 256u + tid; g < NFF4; g += stride) {
            uint fs = g / Q4S;              // feature slab [0,1920)
            uint r4 = g - fs * Q4S;         // float4 within slab
            uint c4 = r4 << 2;
            uint p  = c4 / 59u;
            uint d0 = c4 - 59u * p;
            uint bn = fs / 80u;
            uint chf = fs - 80u * bn;       // 0..79
            uint kc = 59u - d0;
            uint cw = (kc < 4u) ? 1u : 0u;

            const float* src = feats + ((size_t)bn * CC + chf) * PP;
            float vA = src[p];
            float vB = src[p + cw];
            fx4 r;
#pragma unroll
            for (int k = 0; k < 4; ++k) r[k] = ((uint)k >= kc) ? vB : vA;

            uint s = bn * (uint)CHO + 3u + chf;   // output slab index
            ((fx4*)out)[s * Q4S + r4] = r;
        }
    }
}

extern "C" void kernel_launch(void* const* d_in, const int* in_sizes, int n_in,
                              void* d_out, int out_size, void* d_ws, size_t ws_size,
                              hipStream_t stream) {
    const float* feats = (const float*)d_in[0];
    const float* intr  = (const float*)d_in[1];
    const float* extr  = (const float*)d_in[2];
    float* out = (float*)d_out;

    lss_fused<<<WBLK + FBLK, 256, 0, stream>>>(feats, intr, extr, out);
}